// Round 12
// baseline (364.947 us; speedup 1.0000x reference)
//
#include <hip/hip_runtime.h>
#include <hip/hip_cooperative_groups.h>
#include <hip/hip_bf16.h>

namespace cg = cooperative_groups;

#define EPSBN 1e-5f
#define NEG_SLOPE 0.2f

using f32x4  = __attribute__((ext_vector_type(4))) float;
using bf16x8 = __attribute__((ext_vector_type(8))) short;

// ---- workspace layout (float offsets) ----
#define O_Y1B     0            // 14,258,176 ushorts = 7,129,088 f (dead after pac2)
#define O_G1      7129088      // 445,568 f32
#define O_Y2B     7574656      // 6,889,472 ushorts = 3,444,736 f
#define O_G2      11019392     // 107,648
#define O_WKB2    11127040     // 18,432 ushorts = 9,216 f
#define O_WKB3    11136256     // 73,728 ushorts = 36,864 f
#define O_WKB4    11173120     // 294,912 ushorts = 147,456 f
#define O_WADVR   11320576     // 9,216 f32
#define O_ACC     11329792     // 7,168: acc2[8][64][2] acc3[8][128][2] acc4[8][256][2]
#define O_G3      11336960     // 25,088
#define O_Y3B     11362048     // 3,211,264 ushorts = 1,605,632 f
#define O_Y4B     12967680     // 1,179,648 ushorts = 589,824 f
#define A_ACC2    0
#define A_ACC3    1024
#define A_ACC4    3072

__device__ __forceinline__ unsigned short f2bf(float f) {
  union { __hip_bfloat16 b; unsigned short u; } cv;
  cv.b = __float2bfloat16(f);                  // native v_cvt (RNE)
  return cv.u;
}
__device__ __forceinline__ float bf2f(unsigned short u) {
  union { unsigned int i; float f; } x; x.i = (unsigned int)u << 16; return x.f;
}

struct KParams {
  const float *x, *gd, *w1, *b1, *w2, *b2, *w3, *b3, *w4, *b4;
  const float *bg2, *bb2, *bg3, *bb3, *bg4, *bb4, *wadv, *badv;
  float* out;
  float* ws;
};

// ---------------- stage bodies (identical to R9-verified logic) ----------------

// S0: conv1 rows [0,7552) | avgpool1 [7552,9293) | repack [9293,10841) | zero [10841,10848)
__device__ __forceinline__ void prep_body(int vb, int tid, const KParams& p, char* smem) {
  float* ws = p.ws;
  if (vb < 7552) {                          // conv1 + lrelu -> y1 bf16 NHWC
    float* xs  = (float*)smem;              // 360 f
    float* wsm = (float*)(smem + 1536);     // 320 f
    unsigned short* ysm = (unsigned short*)(smem + 2944);  // 1888 us
    const int n = vb / 59, oh = vb % 59;
    for (int i = tid; i < 320; i += 256)
      wsm[i] = (i < 288) ? p.w1[(i & 31) * 9 + (i >> 5)] : p.b1[i - 288];
    const float* src = p.x + ((size_t)n * 120 + oh * 2) * 120;
    for (int i = tid; i < 360; i += 256) xs[i] = src[i];
    __syncthreads();
    const int co = tid & 31;
    const int ow0 = (tid >> 5) * 8;
    float w[9];
#pragma unroll
    for (int k = 0; k < 9; ++k) w[k] = wsm[k * 32 + co];
    const float bias = wsm[288 + co];
#pragma unroll
    for (int j = 0; j < 8; ++j) {
      int ow = ow0 + j;
      if (ow < 59) {
        float acc = bias;
#pragma unroll
        for (int kh = 0; kh < 3; ++kh)
#pragma unroll
          for (int kw = 0; kw < 3; ++kw)
            acc += xs[kh * 120 + ow * 2 + kw] * w[kh * 3 + kw];
        acc = acc >= 0.0f ? acc : NEG_SLOPE * acc;
        ysm[ow * 32 + co] = f2bf(acc);
      }
    }
    __syncthreads();                        // coalesced row flush
    unsigned int* dst = (unsigned int*)((unsigned short*)(ws + O_Y1B) +
                                        (size_t)(n * 59 + oh) * 1888);
    const unsigned int* s2 = (const unsigned int*)ysm;
    for (int i = tid; i < 944; i += 256) dst[i] = s2[i];
    __syncthreads();                        // smem reuse guard
  } else if (vb < 9293) {                   // avgpool gd (120) -> g1 (59)
    int idx = (vb - 7552) * 256 + tid;
    if (idx < 445568) {
      int ow = idx % 59; int t = idx / 59; int oh = t % 59; int n = t / 59;
      const float* gb = p.gd + (n * 120 + oh * 2) * 120 + ow * 2;
      float s = 0.0f;
#pragma unroll
      for (int kh = 0; kh < 3; ++kh)
#pragma unroll
        for (int kw = 0; kw < 3; ++kw) s += gb[kh * 120 + kw];
      ws[O_G1 + idx] = s * (1.0f / 9.0f);
    }
  } else if (vb < 10841) {                  // weight repack -> bf16 [s][co][k]
    int idx = (vb - 9293) * 256 + tid;
    if (idx < 18432) {
      int kk = idx & 31; int t = idx >> 5; int co = t & 63; int tap = t >> 6;
      ((unsigned short*)(ws + O_WKB2))[idx] = f2bf(p.w2[(co * 32 + kk) * 9 + tap]);
    } else if (idx < 92160) {
      int i = idx - 18432;
      int kk = i & 31; int t = i >> 5; int co = t & 127; int t3 = t >> 7;
      int kc = t3 & 1; int tap = t3 >> 1;
      ((unsigned short*)(ws + O_WKB3))[i] = f2bf(p.w3[(co * 64 + kc * 32 + kk) * 9 + tap]);
    } else if (idx < 387072) {
      int i = idx - 92160;
      int kk = i & 31; int t = i >> 5; int co = t & 255; int t3 = t >> 8;
      int kc = t3 & 3; int tap = t3 >> 2;
      ((unsigned short*)(ws + O_WKB4))[i] = f2bf(p.w4[(co * 128 + kc * 32 + kk) * 9 + tap]);
    } else if (idx < 396288) {
      int i = idx - 387072;
      int c = i & 255; int hw = i >> 8;
      ws[O_WADVR + i] = p.wadv[c * 36 + hw] * (1.0f / 96.0f);
    }
  } else {                                  // zero stat accumulators (7168 f)
    int idx = (vb - 10841) * 256 + tid;
    if (idx * 4 < 7168) {
      float4 z = {0.0f, 0.0f, 0.0f, 0.0f};
      *reinterpret_cast<float4*>(ws + O_ACC + idx * 4) = z;
    }
  }
}

__device__ __forceinline__ void pool_body(const float* __restrict__ pin,
                                          float* __restrict__ pgout,
                                          int PHI, int PHO, int vb, int tid, int PTOT) {
  int idx = vb * 256 + tid;
  if (idx < PTOT) {
    int ow = idx % PHO; int t = idx / PHO; int oh = t % PHO; int n = t / PHO;
    const float* gb = pin + (n * PHI + oh * 2) * PHI + ow * 2;
    float s = 0.0f;
#pragma unroll
    for (int kh = 0; kh < 3; ++kh)
#pragma unroll
      for (int kw = 0; kw < 3; ++kw) s += gb[kh * PHI + kw];
    pgout[idx] = s * (1.0f / 9.0f);
  }
}

// Barrier-free MFMA PacConv body. smem: ytile[0,16384) ps[16384,18432) bn[18432,19456)
template <int CI, int CO, int HI, int HO, int NWM, int NWN, bool BN_IN>
__device__ __forceinline__ void pac_body(
    char* smem, int blk, int tid,
    const unsigned short* __restrict__ xb, const float* __restrict__ g,
    const unsigned short* __restrict__ wkb, const float* __restrict__ b,
    const float* __restrict__ gamma, const float* __restrict__ beta,
    const float* __restrict__ accin, float invM,
    unsigned short* __restrict__ yb, float* __restrict__ accout) {
  constexpr int KC   = CI / 32;
  constexpr int S    = 9 * KC;
  constexpr int MBLK = NWM * 32;

  unsigned short* ytile = (unsigned short*)smem;      // [4][2048]
  float* ps   = (float*)(smem + 16384);               // [NWM][CO*2]
  float* bscl = (float*)(smem + 18432);               // [CI]
  float* bshl = bscl + CI;

  const int lane = tid & 63;
  const int wv   = tid >> 6;
  const int wm   = wv / NWN, wn = wv % NWN;
  const int l15  = lane & 15;
  const int g8   = (lane >> 4) * 8;

  if constexpr (BN_IN) {
    if (tid < CI) {
      float s = 0.0f, q = 0.0f;
#pragma unroll
      for (int sl = 0; sl < 8; ++sl) {
        s += accin[(sl * CI + tid) * 2 + 0];
        q += accin[(sl * CI + tid) * 2 + 1];
      }
      float m = s * invM;
      float var = q * invM - m * m;
      float sc = gamma[tid] * rsqrtf(var + EPSBN);
      bscl[tid] = sc;
      bshl[tid] = beta[tid] - m * sc;
    }
    __syncthreads();
  }

  float kk[2][9];
  int   xo[2];
#pragma unroll
  for (int mt = 0; mt < 2; ++mt) {
    int pp = blk * MBLK + wm * 32 + mt * 16 + l15;
    int ow = pp % HO, oh = (pp / HO) % HO, n = pp / (HO * HO);
    const float* gn = g + n * (HI * HI);
    float gc = gn[(oh * 2 + 1) * HI + ow * 2 + 1];
#pragma unroll
    for (int t = 0; t < 9; ++t) {
      float d = gn[(oh * 2 + t / 3) * HI + ow * 2 + (t % 3)] - gc;
      kk[mt][t] = __expf(-0.5f * d * d);
    }
    xo[mt] = ((n * HI + oh * 2) * HI + ow * 2) * CI;
  }

  f32x4 acc[2][4];
#pragma unroll
  for (int nt = 0; nt < 4; ++nt) {
    float bv = b[wn * 64 + nt * 16 + l15];
#pragma unroll
    for (int mt = 0; mt < 2; ++mt) acc[mt][nt] = (f32x4){bv, bv, bv, bv};
  }

#pragma unroll
  for (int i = 0; i < S; ++i) {
    const int t  = i / KC;                   // compile-time
    const int kc = i % KC;                   // compile-time
    const int xoff = ((t / 3) * HI + (t % 3)) * CI + kc * 32 + g8;
    bf16x8 bfv[4];
#pragma unroll
    for (int nt = 0; nt < 4; ++nt)
      bfv[nt] = *(const bf16x8*)(wkb + ((size_t)i * CO + wn * 64 + nt * 16 + l15) * 32 + g8);
    bf16x8 af[2];
#pragma unroll
    for (int mt = 0; mt < 2; ++mt) {
      bf16x8 u = *(const bf16x8*)(xb + xo[mt] + xoff);
      float v[8];
#pragma unroll
      for (int j = 0; j < 8; ++j) v[j] = bf2f((unsigned short)u[j]);
      if constexpr (BN_IN) {
        const int c0 = kc * 32 + g8;
#pragma unroll
        for (int j = 0; j < 8; ++j) v[j] = v[j] * bscl[c0 + j] + bshl[c0 + j];
      }
      const float kv = kk[mt][t];
#pragma unroll
      for (int j = 0; j < 8; ++j) v[j] *= kv;
#pragma unroll
      for (int j = 0; j < 8; ++j) af[mt][j] = (short)f2bf(v[j]);
    }
#pragma unroll
    for (int mt = 0; mt < 2; ++mt)
#pragma unroll
      for (int nt = 0; nt < 4; ++nt)
        acc[mt][nt] = __builtin_amdgcn_mfma_f32_16x16x32_bf16(af[mt], bfv[nt], acc[mt][nt], 0, 0, 0);
  }

  // epilogue: lrelu -> ytile (LDS) + per-channel (sum, sumsq) partials
#pragma unroll
  for (int nt = 0; nt < 4; ++nt) {
    const int co = wn * 64 + nt * 16 + l15;
    float s = 0.0f, q = 0.0f;
#pragma unroll
    for (int mt = 0; mt < 2; ++mt)
#pragma unroll
      for (int r = 0; r < 4; ++r) {
        float v = acc[mt][nt][r];
        v = v >= 0.0f ? v : NEG_SLOPE * v;
        int row = mt * 16 + ((lane >> 4) << 2) + r;
        ytile[wv * 2048 + row * 64 + nt * 16 + l15] = f2bf(v);
        s += v; q += v * v;
      }
    s += __shfl_xor(s, 16, 64); q += __shfl_xor(q, 16, 64);
    s += __shfl_xor(s, 32, 64); q += __shfl_xor(q, 32, 64);
    if (l15 == lane) { ps[wm * (CO * 2) + co * 2 + 0] = s; ps[wm * (CO * 2) + co * 2 + 1] = q; }
  }
  __syncthreads();                           // ytile + ps visible
  {                                          // coalesced tile flush
    unsigned short* dbase = yb + (size_t)(blk * MBLK + wm * 32) * CO + wn * 64;
    const uint4* srcT = (const uint4*)(ytile + wv * 2048);
#pragma unroll
    for (int i = 0; i < 4; ++i) {
      int row = i * 8 + (lane >> 3);
      int u4  = lane & 7;
      *(uint4*)(dbase + (size_t)row * CO + u4 * 8) = srcT[row * 8 + u4];
    }
  }
  if (tid < CO) {
    float s = 0.0f, q = 0.0f;
#pragma unroll
    for (int wmx = 0; wmx < NWM; ++wmx) {
      s += ps[wmx * (CO * 2) + tid * 2];
      q += ps[wmx * (CO * 2) + tid * 2 + 1];
    }
    atomicAdd(&accout[((blk & 7) * CO + tid) * 2 + 0], s);
    atomicAdd(&accout[((blk & 7) * CO + tid) * 2 + 1], q);
  }
  __syncthreads();                           // smem reuse guard
}

__device__ __forceinline__ void linear_body(char* smem, int n, int t, const KParams& p) {
  float* ws = p.ws;
  const unsigned short* y4b = (const unsigned short*)(ws + O_Y4B);
  const float* acc4 = ws + O_ACC + A_ACC4;
  float s0 = 0.0f, q0 = 0.0f;
#pragma unroll
  for (int sl = 0; sl < 8; ++sl) {
    s0 += acc4[(sl * 256 + t) * 2 + 0];
    q0 += acc4[(sl * 256 + t) * 2 + 1];
  }
  float m = s0 * (1.0f / 4608.0f);
  float var = q0 * (1.0f / 4608.0f) - m * m;
  float sc = p.bg4[t] * rsqrtf(var + EPSBN);
  float sh = p.bb4[t] - m * sc;
  const float* wadvr = ws + O_WADVR;
  float s = 0.0f;
  for (int j = t; j < 9216; j += 256)
    s += (bf2f(y4b[n * 9216 + j]) * sc + sh) * wadvr[j];
  float* ss = (float*)smem;
  ss[t] = s; __syncthreads();
  for (int off = 128; off > 0; off >>= 1) {
    if (t < off) ss[t] += ss[t + off];
    __syncthreads();
  }
  if (t == 0) p.out[n] = ss[0] + p.badv[0];
  __syncthreads();                           // smem reuse guard
}

// ---------------- cooperative whole-net kernel (grid-size agnostic) ----------------
__global__ __launch_bounds__(256, 2) void net_kernel(KParams p) {
  __shared__ __align__(16) char smem[19456];
  cg::grid_group grid = cg::this_grid();
  const int tid = threadIdx.x;
  const int bid = blockIdx.x;
  const int gsz = gridDim.x;
  float* ws = p.ws;

  unsigned short* y1b = (unsigned short*)(ws + O_Y1B);
  unsigned short* y2b = (unsigned short*)(ws + O_Y2B);
  unsigned short* y3b = (unsigned short*)(ws + O_Y3B);
  unsigned short* y4b = (unsigned short*)(ws + O_Y4B);
  const unsigned short* wkb2 = (const unsigned short*)(ws + O_WKB2);
  const unsigned short* wkb3 = (const unsigned short*)(ws + O_WKB3);
  const unsigned short* wkb4 = (const unsigned short*)(ws + O_WKB4);
  float* acc2 = ws + O_ACC + A_ACC2;
  float* acc3 = ws + O_ACC + A_ACC3;
  float* acc4 = ws + O_ACC + A_ACC4;

  for (int vb = bid; vb < 10848; vb += gsz) prep_body(vb, tid, p, smem);
  grid.sync();

  for (int vb = bid; vb < 1262; vb += gsz) {
    if (vb < 841)
      pac_body<32, 64, 59, 29, 4, 1, false>(smem, vb, tid, y1b, ws + O_G1, wkb2,
                                            p.b2, nullptr, nullptr, nullptr, 0.0f,
                                            y2b, acc2);
    else
      pool_body(ws + O_G1, ws + O_G2, 59, 29, vb - 841, tid, 107648);
  }
  grid.sync();

  for (int vb = bid; vb < 490; vb += gsz) {
    if (vb < 392)
      pac_body<64, 128, 29, 14, 2, 2, true>(smem, vb, tid, y2b, ws + O_G2, wkb3,
                                            p.b3, p.bg2, p.bb2, acc2, 1.0f / 107648.0f,
                                            y3b, acc3);
    else
      pool_body(ws + O_G2, ws + O_G3, 29, 14, vb - 392, tid, 25088);
  }
  grid.sync();

  for (int vb = bid; vb < 144; vb += gsz)
    pac_body<128, 256, 14, 6, 1, 4, true>(smem, vb, tid, y3b, ws + O_G3, wkb4,
                                          p.b4, p.bg3, p.bb3, acc3, 1.0f / 25088.0f,
                                          y4b, acc4);
  grid.sync();

  for (int vb = bid; vb < 128; vb += gsz) linear_body(smem, vb, tid, p);
}

// ---------------- fallback wrappers (R9-equivalent 5-kernel path) ----------------
__global__ __launch_bounds__(256, 2) void k_prep(KParams p) {
  __shared__ __align__(16) char smem[8192];
  prep_body(blockIdx.x, threadIdx.x, p, smem);
}
__global__ __launch_bounds__(256, 2) void k_s1(KParams p) {
  __shared__ __align__(16) char smem[19456];
  float* ws = p.ws;
  int vb = blockIdx.x;
  if (vb < 841)
    pac_body<32, 64, 59, 29, 4, 1, false>(smem, vb, threadIdx.x,
        (unsigned short*)(ws + O_Y1B), ws + O_G1, (const unsigned short*)(ws + O_WKB2),
        p.b2, nullptr, nullptr, nullptr, 0.0f,
        (unsigned short*)(ws + O_Y2B), ws + O_ACC + A_ACC2);
  else
    pool_body(ws + O_G1, ws + O_G2, 59, 29, vb - 841, threadIdx.x, 107648);
}
__global__ __launch_bounds__(256, 2) void k_s2(KParams p) {
  __shared__ __align__(16) char smem[19456];
  float* ws = p.ws;
  int vb = blockIdx.x;
  if (vb < 392)
    pac_body<64, 128, 29, 14, 2, 2, true>(smem, vb, threadIdx.x,
        (unsigned short*)(ws + O_Y2B), ws + O_G2, (const unsigned short*)(ws + O_WKB3),
        p.b3, p.bg2, p.bb2, ws + O_ACC + A_ACC2, 1.0f / 107648.0f,
        (unsigned short*)(ws + O_Y3B), ws + O_ACC + A_ACC3);
  else
    pool_body(ws + O_G2, ws + O_G3, 29, 14, vb - 392, threadIdx.x, 25088);
}
__global__ __launch_bounds__(256, 2) void k_s3(KParams p) {
  __shared__ __align__(16) char smem[19456];
  float* ws = p.ws;
  pac_body<128, 256, 14, 6, 1, 4, true>(smem, blockIdx.x, threadIdx.x,
      (unsigned short*)(ws + O_Y3B), ws + O_G3, (const unsigned short*)(ws + O_WKB4),
      p.b4, p.bg3, p.bb3, ws + O_ACC + A_ACC3, 1.0f / 25088.0f,
      (unsigned short*)(ws + O_Y4B), ws + O_ACC + A_ACC4);
}
__global__ __launch_bounds__(256, 2) void k_s4(KParams p) {
  __shared__ __align__(16) char smem[1024];
  linear_body(smem, blockIdx.x, threadIdx.x, p);
}

extern "C" void kernel_launch(void* const* d_in, const int* in_sizes, int n_in,
                              void* d_out, int out_size, void* d_ws, size_t ws_size,
                              hipStream_t stream) {
  KParams prm;
  prm.x    = (const float*)d_in[0];
  prm.gd   = (const float*)d_in[1];
  prm.w1   = (const float*)d_in[2];
  prm.b1   = (const float*)d_in[3];
  prm.w2   = (const float*)d_in[4];
  prm.b2   = (const float*)d_in[5];
  prm.w3   = (const float*)d_in[6];
  prm.b3   = (const float*)d_in[7];
  prm.w4   = (const float*)d_in[8];
  prm.b4   = (const float*)d_in[9];
  prm.bg2  = (const float*)d_in[10];
  prm.bb2  = (const float*)d_in[11];
  prm.bg3  = (const float*)d_in[12];
  prm.bb3  = (const float*)d_in[13];
  prm.bg4  = (const float*)d_in[14];
  prm.bb4  = (const float*)d_in[15];
  prm.wadv = (const float*)d_in[16];
  prm.badv = (const float*)d_in[17];
  prm.out  = (float*)d_out;
  prm.ws   = (float*)d_ws;

  // adaptive cooperative grid sizing (pure host queries; capture-safe)
  bool launched = false;
  int dev = 0, numCU = 0, maxB = 0;
  if (hipGetDevice(&dev) == hipSuccess &&
      hipDeviceGetAttribute(&numCU, hipDeviceAttributeMultiprocessorCount, dev) == hipSuccess &&
      hipOccupancyMaxActiveBlocksPerMultiprocessor(&maxB, (const void*)net_kernel, 256, 0) == hipSuccess &&
      numCU > 0 && maxB > 0) {
    long cap = (long)numCU * (long)maxB;
    int grid = cap > 512 ? 512 : (int)cap;
    if (grid >= 64) {
      void* args[] = { (void*)&prm };
      if (hipLaunchCooperativeKernel((const void*)net_kernel, dim3(grid), dim3(256),
                                     args, 0, stream) == hipSuccess)
        launched = true;
    }
  }

  if (!launched) {   // R9-equivalent fallback (verified-pass path)
    k_prep<<<10848, 256, 0, stream>>>(prm);
    k_s1<<<1262, 256, 0, stream>>>(prm);
    k_s2<<<490, 256, 0, stream>>>(prm);
    k_s3<<<144, 256, 0, stream>>>(prm);
    k_s4<<<128, 256, 0, stream>>>(prm);
  }
}

// Round 13
// 129.931 us; speedup vs baseline: 2.8088x; 2.8088x over previous
//
#include <hip/hip_runtime.h>
#include <hip/hip_bf16.h>

#define EPSBN 1e-5f
#define NEG_SLOPE 0.2f

using f32x4  = __attribute__((ext_vector_type(4))) float;
using bf16x8 = __attribute__((ext_vector_type(8))) short;

// ---- workspace layout (float offsets) ----
#define O_Y1B     0            // 14,258,176 ushorts = 7,129,088 f
#define O_G1      7129088      // 445,568 f32
#define O_Y2B     7574656      // 6,889,472 ushorts
#define O_G2      11019392     // 107,648
#define O_WKB2    11127040     // 18,432 ushorts
#define O_WKB3    11136256     // 73,728 ushorts
#define O_WKB4    11173120     // 294,912 ushorts
#define O_WADVR   11320576     // 9,216 f32
#define O_ACC     11329792     // 7,168
#define O_G3      11336960     // 25,088
#define O_Y3B     11362048     // 3,211,264 ushorts
#define O_Y4B     12967680     // 1,179,648 ushorts
#define A_ACC2    0
#define A_ACC3    1024
#define A_ACC4    3072

__device__ __forceinline__ unsigned short f2bf(float f) {
  union { __hip_bfloat16 b; unsigned short u; } cv;
  cv.b = __float2bfloat16(f);
  return cv.u;
}
__device__ __forceinline__ float bf2f(unsigned short u) {
  union { unsigned int i; float f; } x; x.i = (unsigned int)u << 16; return x.f;
}

struct KParams {
  const float *x, *gd, *w1, *b1, *w2, *b2, *w3, *b3, *w4, *b4;
  const float *bg2, *bb2, *bg3, *bb3, *bg4, *bb4, *wadv, *badv;
  float* out;
  float* ws;
};

// S0: conv1 [0,7552) | avgpool1 [7552,9293) | repack [9293,10841) | zero [10841,10848)
__device__ __forceinline__ void prep_body(int vb, int tid, const KParams& p, char* smem) {
  float* ws = p.ws;
  if (vb < 7552) {                          // conv1 + lrelu -> y1 bf16 NHWC
    float* xs  = (float*)smem;              // 360 f
    float* wsm = (float*)(smem + 1536);     // 320 f
    unsigned short* ysm = (unsigned short*)(smem + 2944);  // 1888 us
    const int n = vb / 59, oh = vb % 59;
    for (int i = tid; i < 320; i += 256)
      wsm[i] = (i < 288) ? p.w1[(i & 31) * 9 + (i >> 5)] : p.b1[i - 288];
    const float* src = p.x + ((size_t)n * 120 + oh * 2) * 120;
    for (int i = tid; i < 360; i += 256) xs[i] = src[i];
    __syncthreads();
    const int co = tid & 31;
    const int ow0 = (tid >> 5) * 8;
    float w[9];
#pragma unroll
    for (int k = 0; k < 9; ++k) w[k] = wsm[k * 32 + co];
    const float bias = wsm[288 + co];
#pragma unroll
    for (int j = 0; j < 8; ++j) {
      int ow = ow0 + j;
      if (ow < 59) {
        float acc = bias;
#pragma unroll
        for (int kh = 0; kh < 3; ++kh)
#pragma unroll
          for (int kw = 0; kw < 3; ++kw)
            acc += xs[kh * 120 + ow * 2 + kw] * w[kh * 3 + kw];
        acc = acc >= 0.0f ? acc : NEG_SLOPE * acc;
        ysm[ow * 32 + co] = f2bf(acc);
      }
    }
    __syncthreads();
    unsigned int* dst = (unsigned int*)((unsigned short*)(ws + O_Y1B) +
                                        (size_t)(n * 59 + oh) * 1888);
    const unsigned int* s2 = (const unsigned int*)ysm;
    for (int i = tid; i < 944; i += 256) dst[i] = s2[i];
  } else if (vb < 9293) {                   // avgpool gd (120) -> g1 (59)
    int idx = (vb - 7552) * 256 + tid;
    if (idx < 445568) {
      int ow = idx % 59; int t = idx / 59; int oh = t % 59; int n = t / 59;
      const float* gb = p.gd + (n * 120 + oh * 2) * 120 + ow * 2;
      float s = 0.0f;
#pragma unroll
      for (int kh = 0; kh < 3; ++kh)
#pragma unroll
        for (int kw = 0; kw < 3; ++kw) s += gb[kh * 120 + kw];
      ws[O_G1 + idx] = s * (1.0f / 9.0f);
    }
  } else if (vb < 10841) {                  // weight repack -> bf16 [s][co][k]
    int idx = (vb - 9293) * 256 + tid;
    if (idx < 18432) {
      int kk = idx & 31; int t = idx >> 5; int co = t & 63; int tap = t >> 6;
      ((unsigned short*)(ws + O_WKB2))[idx] = f2bf(p.w2[(co * 32 + kk) * 9 + tap]);
    } else if (idx < 92160) {
      int i = idx - 18432;
      int kk = i & 31; int t = i >> 5; int co = t & 127; int t3 = t >> 7;
      int kc = t3 & 1; int tap = t3 >> 1;
      ((unsigned short*)(ws + O_WKB3))[i] = f2bf(p.w3[(co * 64 + kc * 32 + kk) * 9 + tap]);
    } else if (idx < 387072) {
      int i = idx - 92160;
      int kk = i & 31; int t = i >> 5; int co = t & 255; int t3 = t >> 8;
      int kc = t3 & 3; int tap = t3 >> 2;
      ((unsigned short*)(ws + O_WKB4))[i] = f2bf(p.w4[(co * 128 + kc * 32 + kk) * 9 + tap]);
    } else if (idx < 396288) {
      int i = idx - 387072;
      int c = i & 255; int hw = i >> 8;
      ws[O_WADVR + i] = p.wadv[c * 36 + hw] * (1.0f / 96.0f);
    }
  } else {                                  // zero stat accumulators
    int idx = (vb - 10841) * 256 + tid;
    if (idx * 4 < 7168) {
      float4 z = {0.0f, 0.0f, 0.0f, 0.0f};
      *reinterpret_cast<float4*>(ws + O_ACC + idx * 4) = z;
    }
  }
}

__device__ __forceinline__ void pool_body(const float* __restrict__ pin,
                                          float* __restrict__ pgout,
                                          int PHI, int PHO, int vb, int tid, int PTOT) {
  int idx = vb * 256 + tid;
  if (idx < PTOT) {
    int ow = idx % PHO; int t = idx / PHO; int oh = t % PHO; int n = t / PHO;
    const float* gb = pin + (n * PHI + oh * 2) * PHI + ow * 2;
    float s = 0.0f;
#pragma unroll
    for (int kh = 0; kh < 3; ++kh)
#pragma unroll
      for (int kw = 0; kw < 3; ++kw) s += gb[kh * PHI + kw];
    pgout[idx] = s * (1.0f / 9.0f);
  }
}

// Barrier-free MFMA PacConv body; MT = 16-px m-tiles per wave (1 or 2).
// Block covers MBLK = NWM*MT*16 pixels x CO channels (NWN waves x 64co each).
// smem: ytile[0,16384) ps[16384,18432) bn[18432,19456)
template <int CI, int CO, int HI, int HO, int NWM, int NWN, int MT, bool BN_IN>
__device__ __forceinline__ void pac_body(
    char* smem, int blk, int tid,
    const unsigned short* __restrict__ xb, const float* __restrict__ g,
    const unsigned short* __restrict__ wkb, const float* __restrict__ b,
    const float* __restrict__ gamma, const float* __restrict__ beta,
    const float* __restrict__ accin, float invM,
    unsigned short* __restrict__ yb, float* __restrict__ accout) {
  constexpr int KC   = CI / 32;
  constexpr int S    = 9 * KC;
  constexpr int MBLK = NWM * MT * 16;

  unsigned short* ytile = (unsigned short*)smem;      // [4][2048]
  float* ps   = (float*)(smem + 16384);               // [NWM][CO*2]
  float* bscl = (float*)(smem + 18432);               // [CI]
  float* bshl = bscl + CI;

  const int lane = tid & 63;
  const int wv   = tid >> 6;
  const int wm   = wv / NWN, wn = wv % NWN;
  const int l15  = lane & 15;
  const int g8   = (lane >> 4) * 8;

  if constexpr (BN_IN) {
    if (tid < CI) {
      float s = 0.0f, q = 0.0f;
#pragma unroll
      for (int sl = 0; sl < 8; ++sl) {
        s += accin[(sl * CI + tid) * 2 + 0];
        q += accin[(sl * CI + tid) * 2 + 1];
      }
      float m = s * invM;
      float var = q * invM - m * m;
      float sc = gamma[tid] * rsqrtf(var + EPSBN);
      bscl[tid] = sc;
      bshl[tid] = beta[tid] - m * sc;
    }
    __syncthreads();
  }

  float kk[MT][9];
  int   xo[MT];
#pragma unroll
  for (int mt = 0; mt < MT; ++mt) {
    int pp = blk * MBLK + (wm * MT + mt) * 16 + l15;
    int ow = pp % HO, oh = (pp / HO) % HO, n = pp / (HO * HO);
    const float* gn = g + n * (HI * HI);
    float gc = gn[(oh * 2 + 1) * HI + ow * 2 + 1];
#pragma unroll
    for (int t = 0; t < 9; ++t) {
      float d = gn[(oh * 2 + t / 3) * HI + ow * 2 + (t % 3)] - gc;
      kk[mt][t] = __expf(-0.5f * d * d);
    }
    xo[mt] = ((n * HI + oh * 2) * HI + ow * 2) * CI;
  }

  f32x4 acc[MT][4];
#pragma unroll
  for (int nt = 0; nt < 4; ++nt) {
    float bv = b[wn * 64 + nt * 16 + l15];
#pragma unroll
    for (int mt = 0; mt < MT; ++mt) acc[mt][nt] = (f32x4){bv, bv, bv, bv};
  }

#pragma unroll
  for (int i = 0; i < S; ++i) {
    const int t  = i / KC;                   // compile-time
    const int kc = i % KC;                   // compile-time
    const int xoff = ((t / 3) * HI + (t % 3)) * CI + kc * 32 + g8;
    bf16x8 bfv[4];
#pragma unroll
    for (int nt = 0; nt < 4; ++nt)
      bfv[nt] = *(const bf16x8*)(wkb + ((size_t)i * CO + wn * 64 + nt * 16 + l15) * 32 + g8);
    bf16x8 af[MT];
#pragma unroll
    for (int mt = 0; mt < MT; ++mt) {
      bf16x8 u = *(const bf16x8*)(xb + xo[mt] + xoff);
      float v[8];
#pragma unroll
      for (int j = 0; j < 8; ++j) v[j] = bf2f((unsigned short)u[j]);
      if constexpr (BN_IN) {
        const int c0 = kc * 32 + g8;
#pragma unroll
        for (int j = 0; j < 8; ++j) v[j] = v[j] * bscl[c0 + j] + bshl[c0 + j];
      }
      const float kv = kk[mt][t];
#pragma unroll
      for (int j = 0; j < 8; ++j) v[j] *= kv;
#pragma unroll
      for (int j = 0; j < 8; ++j) af[mt][j] = (short)f2bf(v[j]);
    }
#pragma unroll
    for (int mt = 0; mt < MT; ++mt)
#pragma unroll
      for (int nt = 0; nt < 4; ++nt)
        acc[mt][nt] = __builtin_amdgcn_mfma_f32_16x16x32_bf16(af[mt], bfv[nt], acc[mt][nt], 0, 0, 0);
  }

  // epilogue: lrelu -> ytile (LDS) + per-channel (sum, sumsq) partials
#pragma unroll
  for (int nt = 0; nt < 4; ++nt) {
    const int co = wn * 64 + nt * 16 + l15;
    float s = 0.0f, q = 0.0f;
#pragma unroll
    for (int mt = 0; mt < MT; ++mt)
#pragma unroll
      for (int r = 0; r < 4; ++r) {
        float v = acc[mt][nt][r];
        v = v >= 0.0f ? v : NEG_SLOPE * v;
        int row = mt * 16 + ((lane >> 4) << 2) + r;
        ytile[wv * 2048 + row * 64 + nt * 16 + l15] = f2bf(v);
        s += v; q += v * v;
      }
    s += __shfl_xor(s, 16, 64); q += __shfl_xor(q, 16, 64);
    s += __shfl_xor(s, 32, 64); q += __shfl_xor(q, 32, 64);
    if (l15 == lane) { ps[wm * (CO * 2) + co * 2 + 0] = s; ps[wm * (CO * 2) + co * 2 + 1] = q; }
  }
  __syncthreads();
  {                                          // coalesced tile flush
    unsigned short* dbase = yb + (size_t)(blk * MBLK + wm * MT * 16) * CO + wn * 64;
    const uint4* srcT = (const uint4*)(ytile + wv * 2048);
#pragma unroll
    for (int i = 0; i < MT * 2; ++i) {
      int row = i * 8 + (lane >> 3);
      int u4  = lane & 7;
      *(uint4*)(dbase + (size_t)row * CO + u4 * 8) = srcT[row * 8 + u4];
    }
  }
  if (tid < CO) {
    float s = 0.0f, q = 0.0f;
#pragma unroll
    for (int wmx = 0; wmx < NWM; ++wmx) {
      s += ps[wmx * (CO * 2) + tid * 2];
      q += ps[wmx * (CO * 2) + tid * 2 + 1];
    }
    atomicAdd(&accout[((blk & 7) * CO + tid) * 2 + 0], s);
    atomicAdd(&accout[((blk & 7) * CO + tid) * 2 + 1], q);
  }
}

__device__ __forceinline__ void linear_body(char* smem, int n, int t, const KParams& p) {
  float* ws = p.ws;
  const unsigned short* y4b = (const unsigned short*)(ws + O_Y4B);
  const float* acc4 = ws + O_ACC + A_ACC4;
  float s0 = 0.0f, q0 = 0.0f;
#pragma unroll
  for (int sl = 0; sl < 8; ++sl) {
    s0 += acc4[(sl * 256 + t) * 2 + 0];
    q0 += acc4[(sl * 256 + t) * 2 + 1];
  }
  float m = s0 * (1.0f / 4608.0f);
  float var = q0 * (1.0f / 4608.0f) - m * m;
  float sc = p.bg4[t] * rsqrtf(var + EPSBN);
  float sh = p.bb4[t] - m * sc;
  const float* wadvr = ws + O_WADVR;
  float s = 0.0f;
  for (int j = t; j < 9216; j += 256)
    s += (bf2f(y4b[n * 9216 + j]) * sc + sh) * wadvr[j];
  float* ss = (float*)smem;
  ss[t] = s; __syncthreads();
  for (int off = 128; off > 0; off >>= 1) {
    if (t < off) ss[t] += ss[t + off];
    __syncthreads();
  }
  if (t == 0) p.out[n] = ss[0] + p.badv[0];
}

// ---------------- 5-kernel pipeline (R9-proven structure, MT-tuned grids) ----------------
__global__ __launch_bounds__(256, 2) void k_prep(KParams p) {
  __shared__ __align__(16) char smem[8192];
  prep_body(blockIdx.x, threadIdx.x, p, smem);
}
// S1: pac2 (841 blocks, 128px x 64co) + pool g1->g2 (421)
__global__ __launch_bounds__(256, 2) void k_s1(KParams p) {
  __shared__ __align__(16) char smem[19456];
  float* ws = p.ws;
  int vb = blockIdx.x;
  if (vb < 841)
    pac_body<32, 64, 59, 29, 4, 1, 2, false>(smem, vb, threadIdx.x,
        (unsigned short*)(ws + O_Y1B), ws + O_G1, (const unsigned short*)(ws + O_WKB2),
        p.b2, nullptr, nullptr, nullptr, 0.0f,
        (unsigned short*)(ws + O_Y2B), ws + O_ACC + A_ACC2);
  else
    pool_body(ws + O_G1, ws + O_G2, 59, 29, vb - 841, threadIdx.x, 107648);
}
// S2: pac3 (784 blocks, 32px x 128co; MT=1) + pool g2->g3 (98)
__global__ __launch_bounds__(256, 2) void k_s2(KParams p) {
  __shared__ __align__(16) char smem[19456];
  float* ws = p.ws;
  int vb = blockIdx.x;
  if (vb < 784)
    pac_body<64, 128, 29, 14, 2, 2, 1, true>(smem, vb, threadIdx.x,
        (unsigned short*)(ws + O_Y2B), ws + O_G2, (const unsigned short*)(ws + O_WKB3),
        p.b3, p.bg2, p.bb2, ws + O_ACC + A_ACC2, 1.0f / 107648.0f,
        (unsigned short*)(ws + O_Y3B), ws + O_ACC + A_ACC3);
  else
    pool_body(ws + O_G2, ws + O_G3, 29, 14, vb - 784, threadIdx.x, 25088);
}
// S3: pac4 (288 blocks, 16px x 256co; MT=1)
__global__ __launch_bounds__(256, 2) void k_s3(KParams p) {
  __shared__ __align__(16) char smem[19456];
  float* ws = p.ws;
  pac_body<128, 256, 14, 6, 1, 4, 1, true>(smem, blockIdx.x, threadIdx.x,
      (unsigned short*)(ws + O_Y3B), ws + O_G3, (const unsigned short*)(ws + O_WKB4),
      p.b4, p.bg3, p.bb3, ws + O_ACC + A_ACC3, 1.0f / 25088.0f,
      (unsigned short*)(ws + O_Y4B), ws + O_ACC + A_ACC4);
}
__global__ __launch_bounds__(256, 2) void k_s4(KParams p) {
  __shared__ __align__(16) char smem[1024];
  linear_body(smem, blockIdx.x, threadIdx.x, p);
}

extern "C" void kernel_launch(void* const* d_in, const int* in_sizes, int n_in,
                              void* d_out, int out_size, void* d_ws, size_t ws_size,
                              hipStream_t stream) {
  KParams prm;
  prm.x    = (const float*)d_in[0];
  prm.gd   = (const float*)d_in[1];
  prm.w1   = (const float*)d_in[2];
  prm.b1   = (const float*)d_in[3];
  prm.w2   = (const float*)d_in[4];
  prm.b2   = (const float*)d_in[5];
  prm.w3   = (const float*)d_in[6];
  prm.b3   = (const float*)d_in[7];
  prm.w4   = (const float*)d_in[8];
  prm.b4   = (const float*)d_in[9];
  prm.bg2  = (const float*)d_in[10];
  prm.bb2  = (const float*)d_in[11];
  prm.bg3  = (const float*)d_in[12];
  prm.bb3  = (const float*)d_in[13];
  prm.bg4  = (const float*)d_in[14];
  prm.bb4  = (const float*)d_in[15];
  prm.wadv = (const float*)d_in[16];
  prm.badv = (const float*)d_in[17];
  prm.out  = (float*)d_out;
  prm.ws   = (float*)d_ws;

  k_prep<<<10848, 256, 0, stream>>>(prm);
  k_s1<<<1262, 256, 0, stream>>>(prm);
  k_s2<<<882, 256, 0, stream>>>(prm);
  k_s3<<<288, 256, 0, stream>>>(prm);
  k_s4<<<128, 256, 0, stream>>>(prm);
}

// Round 14
// 105.828 us; speedup vs baseline: 3.4485x; 1.2278x over previous
//
#include <hip/hip_runtime.h>
#include <hip/hip_bf16.h>

#define EPSBN 1e-5f
#define NEG_SLOPE 0.2f

using f32x4  = __attribute__((ext_vector_type(4))) float;
using bf16x8 = __attribute__((ext_vector_type(8))) short;

// ---- workspace layout (float offsets) ----
#define O_Y1B     0            // 14,258,176 ushorts
#define O_G1      7129088      // 445,568 f32
#define O_Y2B     7574656      // 6,889,472 ushorts
#define O_G2      11019392     // 107,648
#define O_WKB2    11127040     // 18,432 ushorts
#define O_WKB3    11136256     // 73,728 ushorts
#define O_WKB4    11173120     // 294,912 ushorts
#define O_WADVR   11320576     // 9,216 f32
#define O_ACC     11329792     // 7,168
#define O_G3      11336960     // 25,088
#define O_Y3B     11362048     // 3,211,264 ushorts
#define O_Y4B     12967680     // 1,179,648 ushorts
#define A_ACC2    0
#define A_ACC3    1024
#define A_ACC4    3072

__device__ __forceinline__ unsigned short f2bf(float f) {
  union { __hip_bfloat16 b; unsigned short u; } cv;
  cv.b = __float2bfloat16(f);
  return cv.u;
}
__device__ __forceinline__ float bf2f(unsigned short u) {
  union { unsigned int i; float f; } x; x.i = (unsigned int)u << 16; return x.f;
}

struct KParams {
  const float *x, *gd, *w1, *b1, *w2, *b2, *w3, *b3, *w4, *b4;
  const float *bg2, *bb2, *bg3, *bb3, *bg4, *bb4, *wadv, *badv;
  float* out;
  float* ws;
};

// S0: conv1 [0,7552) | avgpool1 [7552,9293) | repack [9293,10841) | zero [10841,10848)
__global__ __launch_bounds__(256, 2) void k_prep(KParams p) {
  __shared__ float xs[360];
  __shared__ float wsm[320];
  __shared__ unsigned short ysm[1888];
  const int vb = blockIdx.x, tid = threadIdx.x;
  float* ws = p.ws;
  if (vb < 7552) {                          // conv1 + lrelu -> y1 bf16 NHWC
    const int n = vb / 59, oh = vb % 59;
    for (int i = tid; i < 320; i += 256)
      wsm[i] = (i < 288) ? p.w1[(i & 31) * 9 + (i >> 5)] : p.b1[i - 288];
    const float* src = p.x + ((size_t)n * 120 + oh * 2) * 120;
    for (int i = tid; i < 360; i += 256) xs[i] = src[i];
    __syncthreads();
    const int co = tid & 31;
    const int ow0 = (tid >> 5) * 8;
    float w[9];
#pragma unroll
    for (int k = 0; k < 9; ++k) w[k] = wsm[k * 32 + co];
    const float bias = wsm[288 + co];
#pragma unroll
    for (int j = 0; j < 8; ++j) {
      int ow = ow0 + j;
      if (ow < 59) {
        float acc = bias;
#pragma unroll
        for (int kh = 0; kh < 3; ++kh)
#pragma unroll
          for (int kw = 0; kw < 3; ++kw)
            acc += xs[kh * 120 + ow * 2 + kw] * w[kh * 3 + kw];
        acc = acc >= 0.0f ? acc : NEG_SLOPE * acc;
        ysm[ow * 32 + co] = f2bf(acc);
      }
    }
    __syncthreads();
    unsigned int* dst = (unsigned int*)((unsigned short*)(ws + O_Y1B) +
                                        (size_t)(n * 59 + oh) * 1888);
    const unsigned int* s2 = (const unsigned int*)ysm;
    for (int i = tid; i < 944; i += 256) dst[i] = s2[i];
  } else if (vb < 9293) {                   // avgpool gd -> g1
    int idx = (vb - 7552) * 256 + tid;
    if (idx < 445568) {
      int ow = idx % 59; int t = idx / 59; int oh = t % 59; int n = t / 59;
      const float* gb = p.gd + (n * 120 + oh * 2) * 120 + ow * 2;
      float s = 0.0f;
#pragma unroll
      for (int kh = 0; kh < 3; ++kh)
#pragma unroll
        for (int kw = 0; kw < 3; ++kw) s += gb[kh * 120 + kw];
      ws[O_G1 + idx] = s * (1.0f / 9.0f);
    }
  } else if (vb < 10841) {                  // weight repack -> bf16 [s][co][k]
    int idx = (vb - 9293) * 256 + tid;
    if (idx < 18432) {
      int kk = idx & 31; int t = idx >> 5; int co = t & 63; int tap = t >> 6;
      ((unsigned short*)(ws + O_WKB2))[idx] = f2bf(p.w2[(co * 32 + kk) * 9 + tap]);
    } else if (idx < 92160) {
      int i = idx - 18432;
      int kk = i & 31; int t = i >> 5; int co = t & 127; int t3 = t >> 7;
      int kc = t3 & 1; int tap = t3 >> 1;
      ((unsigned short*)(ws + O_WKB3))[i] = f2bf(p.w3[(co * 64 + kc * 32 + kk) * 9 + tap]);
    } else if (idx < 387072) {
      int i = idx - 92160;
      int kk = i & 31; int t = i >> 5; int co = t & 255; int t3 = t >> 8;
      int kc = t3 & 3; int tap = t3 >> 2;
      ((unsigned short*)(ws + O_WKB4))[i] = f2bf(p.w4[(co * 128 + kc * 32 + kk) * 9 + tap]);
    } else if (idx < 396288) {
      int i = idx - 387072;
      int c = i & 255; int hw = i >> 8;
      ws[O_WADVR + i] = p.wadv[c * 36 + hw] * (1.0f / 96.0f);
    }
  } else {                                  // zero stat accumulators
    int idx = (vb - 10841) * 256 + tid;
    if (idx * 4 < 7168) {
      float4 z = {0.0f, 0.0f, 0.0f, 0.0f};
      *reinterpret_cast<float4*>(ws + O_ACC + idx * 4) = z;
    }
  }
}

__device__ __forceinline__ void pool_body(const float* __restrict__ pin,
                                          float* __restrict__ pgout,
                                          int PHI, int PHO, int vb, int tid,
                                          int PTOT, int THREADS) {
  int idx = vb * THREADS + tid;
  if (idx < PTOT) {
    int ow = idx % PHO; int t = idx / PHO; int oh = t % PHO; int n = t / PHO;
    const float* gb = pin + (n * PHI + oh * 2) * PHI + ow * 2;
    float s = 0.0f;
#pragma unroll
    for (int kh = 0; kh < 3; ++kh)
#pragma unroll
      for (int kw = 0; kw < 3; ++kw) s += gb[kh * PHI + kw];
    pgout[idx] = s * (1.0f / 9.0f);
  }
}

// Barrier-free MFMA PacConv with explicit 1-step register prefetch.
// MT=2 fixed (32px per wave); wave covers 32px x 64co. Block = NWM*NWN waves,
// covering MBLK=NWM*32 px x COB=NWN*64 channels (co-split blocks when COB<CO).
template <int CI, int CO, int COB, int HI, int HO, int NWM, int NWN, bool BN_IN>
__device__ __forceinline__ void pac_body(
    int pxblk, int cob, int tid,
    const unsigned short* __restrict__ xb, const float* __restrict__ g,
    const unsigned short* __restrict__ wkb, const float* __restrict__ b,
    const float* __restrict__ gamma, const float* __restrict__ beta,
    const float* __restrict__ accin, float invM,
    unsigned short* __restrict__ yb, float* __restrict__ accout) {
  constexpr int KC    = CI / 32;
  constexpr int S     = 9 * KC;
  constexpr int MBLK  = NWM * 32;
  constexpr int NWAVE = NWM * NWN;
  constexpr int NTH   = NWAVE * 64;
  constexpr int BSZ   = BN_IN ? CI : 1;

  __shared__ unsigned short ytile[NWAVE][2048];
  __shared__ float ps[NWM][COB * 2];
  __shared__ float bscl[BSZ], bshl[BSZ];

  const int lane = tid & 63;
  const int wv   = tid >> 6;
  const int wm   = wv / NWN, wn = wv % NWN;
  const int l15  = lane & 15;
  const int g8   = (lane >> 4) * 8;
  const int co0  = cob * COB;               // block channel base

  if constexpr (BN_IN) {
    for (int i = tid; i < CI; i += NTH) {
      float s = 0.0f, q = 0.0f;
#pragma unroll
      for (int sl = 0; sl < 8; ++sl) {
        s += accin[(sl * CI + i) * 2 + 0];
        q += accin[(sl * CI + i) * 2 + 1];
      }
      float m = s * invM;
      float var = q * invM - m * m;
      float sc = gamma[i] * rsqrtf(var + EPSBN);
      bscl[i] = sc;
      bshl[i] = beta[i] - m * sc;
    }
    __syncthreads();
  }

  float kk[2][9];
  int   xo[2];
#pragma unroll
  for (int mt = 0; mt < 2; ++mt) {
    int pp = pxblk * MBLK + (wm * 2 + mt) * 16 + l15;
    int ow = pp % HO, oh = (pp / HO) % HO, n = pp / (HO * HO);
    const float* gn = g + n * (HI * HI);
    float gc = gn[(oh * 2 + 1) * HI + ow * 2 + 1];
#pragma unroll
    for (int t = 0; t < 9; ++t) {
      float d = gn[(oh * 2 + t / 3) * HI + ow * 2 + (t % 3)] - gc;
      kk[mt][t] = __expf(-0.5f * d * d);
    }
    xo[mt] = ((n * HI + oh * 2) * HI + ow * 2) * CI;
  }

  f32x4 acc[2][4];
#pragma unroll
  for (int nt = 0; nt < 4; ++nt) {
    float bv = b[co0 + wn * 64 + nt * 16 + l15];
#pragma unroll
    for (int mt = 0; mt < 2; ++mt) acc[mt][nt] = (f32x4){bv, bv, bv, bv};
  }

  // ---- software-pipelined K loop: prefetch step i+1 while processing i ----
  bf16x8 bfvC[4], uC[2];
  {
    // loads for step 0
#pragma unroll
    for (int nt = 0; nt < 4; ++nt)
      bfvC[nt] = *(const bf16x8*)(wkb + ((size_t)0 * CO + co0 + wn * 64 + nt * 16 + l15) * 32 + g8);
    const int xoff0 = 0 * CI + g8;          // t=0,kc=0: ((0/3)*HI+0)*CI + 0*32 + g8
#pragma unroll
    for (int mt = 0; mt < 2; ++mt)
      uC[mt] = *(const bf16x8*)(xb + xo[mt] + xoff0);
  }

#pragma unroll
  for (int i = 0; i < S; ++i) {
    const int t  = i / KC;                   // compile-time under unroll
    const int kc = i % KC;
    bf16x8 bfvN[4], uN[2];
    if (i + 1 < S) {
      const int t2  = (i + 1) / KC;
      const int kc2 = (i + 1) % KC;
      const int xoff2 = ((t2 / 3) * HI + (t2 % 3)) * CI + kc2 * 32 + g8;
#pragma unroll
      for (int nt = 0; nt < 4; ++nt)
        bfvN[nt] = *(const bf16x8*)(wkb + ((size_t)(i + 1) * CO + co0 + wn * 64 + nt * 16 + l15) * 32 + g8);
#pragma unroll
      for (int mt = 0; mt < 2; ++mt)
        uN[mt] = *(const bf16x8*)(xb + xo[mt] + xoff2);
    }
    // process current step
    bf16x8 af[2];
#pragma unroll
    for (int mt = 0; mt < 2; ++mt) {
      float v[8];
#pragma unroll
      for (int j = 0; j < 8; ++j) v[j] = bf2f((unsigned short)uC[mt][j]);
      if constexpr (BN_IN) {
        const int c0 = kc * 32 + g8;
#pragma unroll
        for (int j = 0; j < 8; ++j) v[j] = v[j] * bscl[c0 + j] + bshl[c0 + j];
      }
      const float kv = kk[mt][t];
#pragma unroll
      for (int j = 0; j < 8; ++j) v[j] *= kv;
#pragma unroll
      for (int j = 0; j < 8; ++j) af[mt][j] = (short)f2bf(v[j]);
    }
#pragma unroll
    for (int mt = 0; mt < 2; ++mt)
#pragma unroll
      for (int nt = 0; nt < 4; ++nt)
        acc[mt][nt] = __builtin_amdgcn_mfma_f32_16x16x32_bf16(af[mt], bfvC[nt], acc[mt][nt], 0, 0, 0);
    if (i + 1 < S) {
#pragma unroll
      for (int nt = 0; nt < 4; ++nt) bfvC[nt] = bfvN[nt];
      uC[0] = uN[0]; uC[1] = uN[1];
    }
  }

  // epilogue: lrelu -> ytile + per-channel (sum, sumsq) partials
#pragma unroll
  for (int nt = 0; nt < 4; ++nt) {
    const int coL = wn * 64 + nt * 16 + l15;       // channel within block
    float s = 0.0f, q = 0.0f;
#pragma unroll
    for (int mt = 0; mt < 2; ++mt)
#pragma unroll
      for (int r = 0; r < 4; ++r) {
        float v = acc[mt][nt][r];
        v = v >= 0.0f ? v : NEG_SLOPE * v;
        int row = mt * 16 + ((lane >> 4) << 2) + r;
        ytile[wv][row * 64 + nt * 16 + l15] = f2bf(v);
        s += v; q += v * v;
      }
    s += __shfl_xor(s, 16, 64); q += __shfl_xor(q, 16, 64);
    s += __shfl_xor(s, 32, 64); q += __shfl_xor(q, 32, 64);
    if (l15 == lane) { ps[wm][coL * 2 + 0] = s; ps[wm][coL * 2 + 1] = q; }
  }
  __syncthreads();
  {                                          // coalesced tile flush (32 rows x 64co per wave)
    unsigned short* dbase = yb + (size_t)(pxblk * MBLK + wm * 32) * CO + co0 + wn * 64;
    const uint4* srcT = (const uint4*)ytile[wv];
#pragma unroll
    for (int i = 0; i < 4; ++i) {
      int row = i * 8 + (lane >> 3);
      int u4  = lane & 7;
      *(uint4*)(dbase + (size_t)row * CO + u4 * 8) = srcT[row * 8 + u4];
    }
  }
  if (tid < COB) {
    float s = 0.0f, q = 0.0f;
#pragma unroll
    for (int wmx = 0; wmx < NWM; ++wmx) {
      s += ps[wmx][tid * 2];
      q += ps[wmx][tid * 2 + 1];
    }
    atomicAdd(&accout[((pxblk & 7) * CO + co0 + tid) * 2 + 0], s);
    atomicAdd(&accout[((pxblk & 7) * CO + co0 + tid) * 2 + 1], q);
  }
}

// S1: pac2 (841 blocks, 128px x 64co, 4 waves) + pool g1->g2 (421)
__global__ __launch_bounds__(256, 2) void k_s1(KParams p) {
  float* ws = p.ws;
  int vb = blockIdx.x;
  if (vb < 841)
    pac_body<32, 64, 64, 59, 29, 4, 1, false>(vb, 0, threadIdx.x,
        (unsigned short*)(ws + O_Y1B), ws + O_G1, (const unsigned short*)(ws + O_WKB2),
        p.b2, nullptr, nullptr, nullptr, 0.0f,
        (unsigned short*)(ws + O_Y2B), ws + O_ACC + A_ACC2);
  else
    pool_body(ws + O_G1, ws + O_G2, 59, 29, vb - 841, threadIdx.x, 107648, 256);
}
// S2: pac3 (784 blocks, 32px x 128co, 2 waves of 128 thr) + pool g2->g3 (196)
__global__ __launch_bounds__(128, 2) void k_s2(KParams p) {
  float* ws = p.ws;
  int vb = blockIdx.x;
  if (vb < 784)
    pac_body<64, 128, 128, 29, 14, 1, 2, true>(vb, 0, threadIdx.x,
        (unsigned short*)(ws + O_Y2B), ws + O_G2, (const unsigned short*)(ws + O_WKB3),
        p.b3, p.bg2, p.bb2, ws + O_ACC + A_ACC2, 1.0f / 107648.0f,
        (unsigned short*)(ws + O_Y3B), ws + O_ACC + A_ACC3);
  else
    pool_body(ws + O_G2, ws + O_G3, 29, 14, vb - 784, threadIdx.x, 25088, 128);
}
// S3: pac4 (288 blocks = 144 px-blocks x 2 co-blocks, 32px x 128co, 128 thr)
__global__ __launch_bounds__(128, 2) void k_s3(KParams p) {
  float* ws = p.ws;
  int pxblk = blockIdx.x >> 1, cob = blockIdx.x & 1;
  pac_body<128, 256, 128, 14, 6, 1, 2, true>(pxblk, cob, threadIdx.x,
      (unsigned short*)(ws + O_Y3B), ws + O_G3, (const unsigned short*)(ws + O_WKB4),
      p.b4, p.bg3, p.bb3, ws + O_ACC + A_ACC3, 1.0f / 25088.0f,
      (unsigned short*)(ws + O_Y4B), ws + O_ACC + A_ACC4);
}
__global__ __launch_bounds__(256, 2) void k_s4(KParams p) {
  __shared__ float ss[256];
  float* ws = p.ws;
  int n = blockIdx.x, t = threadIdx.x;
  const unsigned short* y4b = (const unsigned short*)(ws + O_Y4B);
  const float* acc4 = ws + O_ACC + A_ACC4;
  float s0 = 0.0f, q0 = 0.0f;
#pragma unroll
  for (int sl = 0; sl < 8; ++sl) {
    s0 += acc4[(sl * 256 + t) * 2 + 0];
    q0 += acc4[(sl * 256 + t) * 2 + 1];
  }
  float m = s0 * (1.0f / 4608.0f);
  float var = q0 * (1.0f / 4608.0f) - m * m;
  float sc = p.bg4[t] * rsqrtf(var + EPSBN);
  float sh = p.bb4[t] - m * sc;
  const float* wadvr = ws + O_WADVR;
  float s = 0.0f;
  for (int j = t; j < 9216; j += 256)
    s += (bf2f(y4b[n * 9216 + j]) * sc + sh) * wadvr[j];
  ss[t] = s; __syncthreads();
  for (int off = 128; off > 0; off >>= 1) {
    if (t < off) ss[t] += ss[t + off];
    __syncthreads();
  }
  if (t == 0) p.out[n] = ss[0] + p.badv[0];
}

extern "C" void kernel_launch(void* const* d_in, const int* in_sizes, int n_in,
                              void* d_out, int out_size, void* d_ws, size_t ws_size,
                              hipStream_t stream) {
  KParams prm;
  prm.x    = (const float*)d_in[0];
  prm.gd   = (const float*)d_in[1];
  prm.w1   = (const float*)d_in[2];
  prm.b1   = (const float*)d_in[3];
  prm.w2   = (const float*)d_in[4];
  prm.b2   = (const float*)d_in[5];
  prm.w3   = (const float*)d_in[6];
  prm.b3   = (const float*)d_in[7];
  prm.w4   = (const float*)d_in[8];
  prm.b4   = (const float*)d_in[9];
  prm.bg2  = (const float*)d_in[10];
  prm.bb2  = (const float*)d_in[11];
  prm.bg3  = (const float*)d_in[12];
  prm.bb3  = (const float*)d_in[13];
  prm.bg4  = (const float*)d_in[14];
  prm.bb4  = (const float*)d_in[15];
  prm.wadv = (const float*)d_in[16];
  prm.badv = (const float*)d_in[17];
  prm.out  = (float*)d_out;
  prm.ws   = (float*)d_ws;

  k_prep<<<10848, 256, 0, stream>>>(prm);
  k_s1<<<1262, 256, 0, stream>>>(prm);
  k_s2<<<980, 128, 0, stream>>>(prm);
  k_s3<<<288, 128, 0, stream>>>(prm);
  k_s4<<<128, 256, 0, stream>>>(prm);
}

// Round 15
// 102.363 us; speedup vs baseline: 3.5652x; 1.0338x over previous
//
#include <hip/hip_runtime.h>
#include <hip/hip_bf16.h>

#define EPSBN 1e-5f
#define NEG_SLOPE 0.2f

using f32x4  = __attribute__((ext_vector_type(4))) float;
using bf16x8 = __attribute__((ext_vector_type(8))) short;

// ---- workspace layout (float offsets) ----
#define O_Y1B     0            // 14,258,176 ushorts
#define O_G1      7129088      // 445,568 f32
#define O_Y2B     7574656      // 6,889,472 ushorts
#define O_G2      11019392     // 107,648
#define O_WKB2    11127040     // 18,432 ushorts
#define O_WKB3    11136256     // 73,728 ushorts
#define O_WKB4    11173120     // 294,912 ushorts
#define O_WADVR   11320576     // 9,216 f32
#define O_ACC     11329792     // 7,168
#define O_G3      11336960     // 25,088
#define O_Y3B     11362048     // 3,211,264 ushorts
#define O_Y4B     12967680     // 1,179,648 ushorts
#define A_ACC2    0
#define A_ACC3    1024
#define A_ACC4    3072

__device__ __forceinline__ unsigned short f2bf(float f) {
  union { __hip_bfloat16 b; unsigned short u; } cv;
  cv.b = __float2bfloat16(f);
  return cv.u;
}
__device__ __forceinline__ float bf2f(unsigned short u) {
  union { unsigned int i; float f; } x; x.i = (unsigned int)u << 16; return x.f;
}

struct KParams {
  const float *x, *gd, *w1, *b1, *w2, *b2, *w3, *b3, *w4, *b4;
  const float *bg2, *bb2, *bg3, *bb3, *bg4, *bb4, *wadv, *badv;
  float* out;
  float* ws;
};

// S0: conv1 [0,7552) | avgpool1 [7552,9293) | repack [9293,10841) | zero [10841,10848)
__global__ __launch_bounds__(256, 2) void k_prep(KParams p) {
  __shared__ float xs[360];
  __shared__ float wsm[320];
  __shared__ unsigned short ysm[1888];
  const int vb = blockIdx.x, tid = threadIdx.x;
  float* ws = p.ws;
  if (vb < 7552) {                          // conv1 + lrelu -> y1 bf16 NHWC
    const int n = vb / 59, oh = vb % 59;
    for (int i = tid; i < 320; i += 256)
      wsm[i] = (i < 288) ? p.w1[(i & 31) * 9 + (i >> 5)] : p.b1[i - 288];
    const float* src = p.x + ((size_t)n * 120 + oh * 2) * 120;
    for (int i = tid; i < 360; i += 256) xs[i] = src[i];
    __syncthreads();
    const int co = tid & 31;
    const int ow0 = (tid >> 5) * 8;
    float w[9];
#pragma unroll
    for (int k = 0; k < 9; ++k) w[k] = wsm[k * 32 + co];
    const float bias = wsm[288 + co];
#pragma unroll
    for (int j = 0; j < 8; ++j) {
      int ow = ow0 + j;
      if (ow < 59) {
        float acc = bias;
#pragma unroll
        for (int kh = 0; kh < 3; ++kh)
#pragma unroll
          for (int kw = 0; kw < 3; ++kw)
            acc += xs[kh * 120 + ow * 2 + kw] * w[kh * 3 + kw];
        acc = acc >= 0.0f ? acc : NEG_SLOPE * acc;
        ysm[ow * 32 + co] = f2bf(acc);
      }
    }
    __syncthreads();
    unsigned int* dst = (unsigned int*)((unsigned short*)(ws + O_Y1B) +
                                        (size_t)(n * 59 + oh) * 1888);
    const unsigned int* s2 = (const unsigned int*)ysm;
    for (int i = tid; i < 944; i += 256) dst[i] = s2[i];
  } else if (vb < 9293) {                   // avgpool gd -> g1
    int idx = (vb - 7552) * 256 + tid;
    if (idx < 445568) {
      int ow = idx % 59; int t = idx / 59; int oh = t % 59; int n = t / 59;
      const float* gb = p.gd + (n * 120 + oh * 2) * 120 + ow * 2;
      float s = 0.0f;
#pragma unroll
      for (int kh = 0; kh < 3; ++kh)
#pragma unroll
        for (int kw = 0; kw < 3; ++kw) s += gb[kh * 120 + kw];
      ws[O_G1 + idx] = s * (1.0f / 9.0f);
    }
  } else if (vb < 10841) {                  // weight repack -> bf16 [s][co][k]
    int idx = (vb - 9293) * 256 + tid;
    if (idx < 18432) {
      int kk = idx & 31; int t = idx >> 5; int co = t & 63; int tap = t >> 6;
      ((unsigned short*)(ws + O_WKB2))[idx] = f2bf(p.w2[(co * 32 + kk) * 9 + tap]);
    } else if (idx < 92160) {
      int i = idx - 18432;
      int kk = i & 31; int t = i >> 5; int co = t & 127; int t3 = t >> 7;
      int kc = t3 & 1; int tap = t3 >> 1;
      ((unsigned short*)(ws + O_WKB3))[i] = f2bf(p.w3[(co * 64 + kc * 32 + kk) * 9 + tap]);
    } else if (idx < 387072) {
      int i = idx - 92160;
      int kk = i & 31; int t = i >> 5; int co = t & 255; int t3 = t >> 8;
      int kc = t3 & 3; int tap = t3 >> 2;
      ((unsigned short*)(ws + O_WKB4))[i] = f2bf(p.w4[(co * 128 + kc * 32 + kk) * 9 + tap]);
    } else if (idx < 396288) {
      int i = idx - 387072;
      int c = i & 255; int hw = i >> 8;
      ws[O_WADVR + i] = p.wadv[c * 36 + hw] * (1.0f / 96.0f);
    }
  } else {                                  // zero stat accumulators
    int idx = (vb - 10841) * 256 + tid;
    if (idx * 4 < 7168) {
      float4 z = {0.0f, 0.0f, 0.0f, 0.0f};
      *reinterpret_cast<float4*>(ws + O_ACC + idx * 4) = z;
    }
  }
}

__device__ __forceinline__ void pool_body(const float* __restrict__ pin,
                                          float* __restrict__ pgout,
                                          int PHI, int PHO, int vb, int tid,
                                          int PTOT, int THREADS) {
  int idx = vb * THREADS + tid;
  if (idx < PTOT) {
    int ow = idx % PHO; int t = idx / PHO; int oh = t % PHO; int n = t / PHO;
    const float* gb = pin + (n * PHI + oh * 2) * PHI + ow * 2;
    float s = 0.0f;
#pragma unroll
    for (int kh = 0; kh < 3; ++kh)
#pragma unroll
      for (int kw = 0; kw < 3; ++kw) s += gb[kh * PHI + kw];
    pgout[idx] = s * (1.0f / 9.0f);
  }
}

// ---- pac2 body: full-B-in-LDS (46 KB, pad-40 rows), 2-deep A prefetch ----
// 4 waves x (32px x 64co); block covers 128 px. S=9, KC=1.
__device__ __forceinline__ void pac2_body(
    int pxblk, int tid,
    const unsigned short* __restrict__ xb, const float* __restrict__ g,
    const unsigned short* __restrict__ wkb, const float* __restrict__ b,
    unsigned short* __restrict__ yb, float* __restrict__ accout) {
  constexpr int HI = 59, HO = 29, CI = 32, CO = 64, S = 9;
  __shared__ unsigned short Bsh[576 * 40];          // 46080 B (row = s*64+co)
  __shared__ unsigned short ytile[4][2048];         // 16384 B
  __shared__ float ps[4][128];                      // 2048 B  -> 63.0 KB total

  const int lane = tid & 63;
  const int wv   = tid >> 6;                        // wm = wv (NWN=1)
  const int l15  = lane & 15;
  const int g8   = (lane >> 4) * 8;

  // stage B once: 576 rows x 64B -> pad-40 rows
  for (int j = tid; j < 2304; j += 256) {
    int row = j >> 2, q = j & 3;
    *(uint4*)&Bsh[row * 40 + q * 8] = *(const uint4*)(wkb + row * 32 + q * 8);
  }

  float kk[2][9];
  int   xo[2];
#pragma unroll
  for (int mt = 0; mt < 2; ++mt) {
    int pp = pxblk * 128 + (wv * 2 + mt) * 16 + l15;
    int ow = pp % HO, oh = (pp / HO) % HO, n = pp / (HO * HO);
    const float* gn = g + n * (HI * HI);
    float gc = gn[(oh * 2 + 1) * HI + ow * 2 + 1];
#pragma unroll
    for (int t = 0; t < 9; ++t) {
      float d = gn[(oh * 2 + t / 3) * HI + ow * 2 + (t % 3)] - gc;
      kk[mt][t] = __expf(-0.5f * d * d);
    }
    xo[mt] = ((n * HI + oh * 2) * HI + ow * 2) * CI;
  }

  f32x4 acc[2][4];
#pragma unroll
  for (int nt = 0; nt < 4; ++nt) {
    float bv = b[nt * 16 + l15];
#pragma unroll
    for (int mt = 0; mt < 2; ++mt) acc[mt][nt] = (f32x4){bv, bv, bv, bv};
  }

  auto loadA = [&](int i, bf16x8* dst) {
    const int xoff = ((i / 3) * HI + (i % 3)) * CI + g8;
#pragma unroll
    for (int mt = 0; mt < 2; ++mt)
      dst[mt] = *(const bf16x8*)(xb + xo[mt] + xoff);
  };

  bf16x8 bA[3][2];
  loadA(0, bA[0]); loadA(1, bA[1]);
  __syncthreads();                                  // Bsh ready

#pragma unroll
  for (int i = 0; i < S; ++i) {
    if (i + 2 < S) loadA(i + 2, bA[(i + 2) % 3]);
    bf16x8 bf[4];
#pragma unroll
    for (int nt = 0; nt < 4; ++nt)
      bf[nt] = *(const bf16x8*)&Bsh[(i * 64 + nt * 16 + l15) * 40 + g8];
    bf16x8 af[2];
#pragma unroll
    for (int mt = 0; mt < 2; ++mt) {
      float v[8];
#pragma unroll
      for (int j = 0; j < 8; ++j) v[j] = bf2f((unsigned short)bA[i % 3][mt][j]);
      const float kv = kk[mt][i];
#pragma unroll
      for (int j = 0; j < 8; ++j) v[j] *= kv;
#pragma unroll
      for (int j = 0; j < 8; ++j) af[mt][j] = (short)f2bf(v[j]);
    }
#pragma unroll
    for (int mt = 0; mt < 2; ++mt)
#pragma unroll
      for (int nt = 0; nt < 4; ++nt)
        acc[mt][nt] = __builtin_amdgcn_mfma_f32_16x16x32_bf16(af[mt], bf[nt], acc[mt][nt], 0, 0, 0);
  }

  // epilogue: lrelu -> ytile + per-channel partials
#pragma unroll
  for (int nt = 0; nt < 4; ++nt) {
    const int coL = nt * 16 + l15;
    float s = 0.0f, q = 0.0f;
#pragma unroll
    for (int mt = 0; mt < 2; ++mt)
#pragma unroll
      for (int r = 0; r < 4; ++r) {
        float v = acc[mt][nt][r];
        v = v >= 0.0f ? v : NEG_SLOPE * v;
        int row = mt * 16 + ((lane >> 4) << 2) + r;
        ytile[wv][row * 64 + nt * 16 + l15] = f2bf(v);
        s += v; q += v * v;
      }
    s += __shfl_xor(s, 16, 64); q += __shfl_xor(q, 16, 64);
    s += __shfl_xor(s, 32, 64); q += __shfl_xor(q, 32, 64);
    if (l15 == lane) { ps[wv][coL * 2 + 0] = s; ps[wv][coL * 2 + 1] = q; }
  }
  __syncthreads();
  {
    unsigned short* dbase = yb + (size_t)(pxblk * 128 + wv * 32) * CO;
    const uint4* srcT = (const uint4*)ytile[wv];
#pragma unroll
    for (int i = 0; i < 4; ++i) {
      int row = i * 8 + (lane >> 3);
      int u4  = lane & 7;
      *(uint4*)(dbase + (size_t)row * CO + u4 * 8) = srcT[row * 8 + u4];
    }
  }
  if (tid < 64) {
    float s = ps[0][tid * 2] + ps[1][tid * 2] + ps[2][tid * 2] + ps[3][tid * 2];
    float q = ps[0][tid * 2 + 1] + ps[1][tid * 2 + 1] + ps[2][tid * 2 + 1] + ps[3][tid * 2 + 1];
    atomicAdd(&accout[((pxblk & 7) * CO + tid) * 2 + 0], s);
    atomicAdd(&accout[((pxblk & 7) * CO + tid) * 2 + 1], q);
  }
}

// ---- pac3/pac4 body: global B, 2-deep prefetch on A and B ----
// 2 waves (NWN=2) x (32px x 64co) = 32px x 128co per block; COB=128.
template <int CI, int CO, int HI, int HO>
__device__ __forceinline__ void pacg_body(
    int pxblk, int cob, int tid,
    const unsigned short* __restrict__ xb, const float* __restrict__ g,
    const unsigned short* __restrict__ wkb, const float* __restrict__ b,
    const float* __restrict__ gamma, const float* __restrict__ beta,
    const float* __restrict__ accin, float invM,
    unsigned short* __restrict__ yb, float* __restrict__ accout) {
  constexpr int KC  = CI / 32;
  constexpr int S   = 9 * KC;
  constexpr int COB = 128;

  __shared__ unsigned short ytile[2][2048];
  __shared__ float ps[COB * 2];
  __shared__ float bscl[CI], bshl[CI];

  const int lane = tid & 63;
  const int wn   = tid >> 6;          // NWM=1: wave index = co-tile
  const int l15  = lane & 15;
  const int g8   = (lane >> 4) * 8;
  const int co0  = cob * COB;

  for (int i = tid; i < CI; i += 128) {
    float s = 0.0f, q = 0.0f;
#pragma unroll
    for (int sl = 0; sl < 8; ++sl) {
      s += accin[(sl * CI + i) * 2 + 0];
      q += accin[(sl * CI + i) * 2 + 1];
    }
    float m = s * invM;
    float var = q * invM - m * m;
    float sc = gamma[i] * rsqrtf(var + EPSBN);
    bscl[i] = sc;
    bshl[i] = beta[i] - m * sc;
  }
  __syncthreads();

  float kk[2][9];
  int   xo[2];
#pragma unroll
  for (int mt = 0; mt < 2; ++mt) {
    int pp = pxblk * 32 + mt * 16 + l15;
    int ow = pp % HO, oh = (pp / HO) % HO, n = pp / (HO * HO);
    const float* gn = g + n * (HI * HI);
    float gc = gn[(oh * 2 + 1) * HI + ow * 2 + 1];
#pragma unroll
    for (int t = 0; t < 9; ++t) {
      float d = gn[(oh * 2 + t / 3) * HI + ow * 2 + (t % 3)] - gc;
      kk[mt][t] = __expf(-0.5f * d * d);
    }
    xo[mt] = ((n * HI + oh * 2) * HI + ow * 2) * CI;
  }

  f32x4 acc[2][4];
#pragma unroll
  for (int nt = 0; nt < 4; ++nt) {
    float bv = b[co0 + wn * 64 + nt * 16 + l15];
#pragma unroll
    for (int mt = 0; mt < 2; ++mt) acc[mt][nt] = (f32x4){bv, bv, bv, bv};
  }

  auto loadStep = [&](int i, bf16x8* dA, bf16x8* dB) {
    const int t  = i / KC;
    const int kc = i % KC;
    const int xoff = ((t / 3) * HI + (t % 3)) * CI + kc * 32 + g8;
#pragma unroll
    for (int mt = 0; mt < 2; ++mt)
      dA[mt] = *(const bf16x8*)(xb + xo[mt] + xoff);
#pragma unroll
    for (int nt = 0; nt < 4; ++nt)
      dB[nt] = *(const bf16x8*)(wkb + ((size_t)i * CO + co0 + wn * 64 + nt * 16 + l15) * 32 + g8);
  };

  bf16x8 bA[3][2], bB[3][4];
  loadStep(0, bA[0], bB[0]);
  loadStep(1, bA[1], bB[1]);

#pragma unroll
  for (int i = 0; i < S; ++i) {
    if (i + 2 < S) loadStep(i + 2, bA[(i + 2) % 3], bB[(i + 2) % 3]);
    const int t  = i / KC;
    const int kc = i % KC;
    bf16x8 af[2];
#pragma unroll
    for (int mt = 0; mt < 2; ++mt) {
      float v[8];
#pragma unroll
      for (int j = 0; j < 8; ++j) v[j] = bf2f((unsigned short)bA[i % 3][mt][j]);
      const int c0 = kc * 32 + g8;
#pragma unroll
      for (int j = 0; j < 8; ++j) v[j] = v[j] * bscl[c0 + j] + bshl[c0 + j];
      const float kv = kk[mt][t];
#pragma unroll
      for (int j = 0; j < 8; ++j) v[j] *= kv;
#pragma unroll
      for (int j = 0; j < 8; ++j) af[mt][j] = (short)f2bf(v[j]);
    }
#pragma unroll
    for (int mt = 0; mt < 2; ++mt)
#pragma unroll
      for (int nt = 0; nt < 4; ++nt)
        acc[mt][nt] = __builtin_amdgcn_mfma_f32_16x16x32_bf16(af[mt], bB[i % 3][nt], acc[mt][nt], 0, 0, 0);
  }

  // epilogue
#pragma unroll
  for (int nt = 0; nt < 4; ++nt) {
    const int coL = wn * 64 + nt * 16 + l15;
    float s = 0.0f, q = 0.0f;
#pragma unroll
    for (int mt = 0; mt < 2; ++mt)
#pragma unroll
      for (int r = 0; r < 4; ++r) {
        float v = acc[mt][nt][r];
        v = v >= 0.0f ? v : NEG_SLOPE * v;
        int row = mt * 16 + ((lane >> 4) << 2) + r;
        ytile[wn][row * 64 + nt * 16 + l15] = f2bf(v);
        s += v; q += v * v;
      }
    s += __shfl_xor(s, 16, 64); q += __shfl_xor(q, 16, 64);
    s += __shfl_xor(s, 32, 64); q += __shfl_xor(q, 32, 64);
    if (l15 == lane) { ps[coL * 2 + 0] = s; ps[coL * 2 + 1] = q; }
  }
  __syncthreads();
  {
    unsigned short* dbase = yb + (size_t)(pxblk * 32) * CO + co0 + wn * 64;
    const uint4* srcT = (const uint4*)ytile[wn];
#pragma unroll
    for (int i = 0; i < 4; ++i) {
      int row = i * 8 + (lane >> 3);
      int u4  = lane & 7;
      *(uint4*)(dbase + (size_t)row * CO + u4 * 8) = srcT[row * 8 + u4];
    }
  }
  if (tid < COB) {
    atomicAdd(&accout[((pxblk & 7) * CO + co0 + tid) * 2 + 0], ps[tid * 2]);
    atomicAdd(&accout[((pxblk & 7) * CO + co0 + tid) * 2 + 1], ps[tid * 2 + 1]);
  }
}

// S1: pac2 (841 blocks) + pool g1->g2 (421)
__global__ __launch_bounds__(256, 2) void k_s1(KParams p) {
  float* ws = p.ws;
  int vb = blockIdx.x;
  if (vb < 841)
    pac2_body(vb, threadIdx.x,
        (unsigned short*)(ws + O_Y1B), ws + O_G1, (const unsigned short*)(ws + O_WKB2),
        p.b2, (unsigned short*)(ws + O_Y2B), ws + O_ACC + A_ACC2);
  else
    pool_body(ws + O_G1, ws + O_G2, 59, 29, vb - 841, threadIdx.x, 107648, 256);
}
// S2: pac3 (784 blocks, 32px x 128co, 128 thr) + pool g2->g3 (196)
__global__ __launch_bounds__(128, 2) void k_s2(KParams p) {
  float* ws = p.ws;
  int vb = blockIdx.x;
  if (vb < 784)
    pacg_body<64, 128, 29, 14>(vb, 0, threadIdx.x,
        (unsigned short*)(ws + O_Y2B), ws + O_G2, (const unsigned short*)(ws + O_WKB3),
        p.b3, p.bg2, p.bb2, ws + O_ACC + A_ACC2, 1.0f / 107648.0f,
        (unsigned short*)(ws + O_Y3B), ws + O_ACC + A_ACC3);
  else
    pool_body(ws + O_G2, ws + O_G3, 29, 14, vb - 784, threadIdx.x, 25088, 128);
}
// S3: pac4 (288 blocks = 144 px-blocks x 2 co-blocks, 128 thr)
__global__ __launch_bounds__(128, 2) void k_s3(KParams p) {
  float* ws = p.ws;
  int pxblk = blockIdx.x >> 1, cob = blockIdx.x & 1;
  pacg_body<128, 256, 14, 6>(pxblk, cob, threadIdx.x,
      (unsigned short*)(ws + O_Y3B), ws + O_G3, (const unsigned short*)(ws + O_WKB4),
      p.b4, p.bg3, p.bb3, ws + O_ACC + A_ACC3, 1.0f / 25088.0f,
      (unsigned short*)(ws + O_Y4B), ws + O_ACC + A_ACC4);
}
__global__ __launch_bounds__(256, 2) void k_s4(KParams p) {
  __shared__ float ss[256];
  float* ws = p.ws;
  int n = blockIdx.x, t = threadIdx.x;
  const unsigned short* y4b = (const unsigned short*)(ws + O_Y4B);
  const float* acc4 = ws + O_ACC + A_ACC4;
  float s0 = 0.0f, q0 = 0.0f;
#pragma unroll
  for (int sl = 0; sl < 8; ++sl) {
    s0 += acc4[(sl * 256 + t) * 2 + 0];
    q0 += acc4[(sl * 256 + t) * 2 + 1];
  }
  float m = s0 * (1.0f / 4608.0f);
  float var = q0 * (1.0f / 4608.0f) - m * m;
  float sc = p.bg4[t] * rsqrtf(var + EPSBN);
  float sh = p.bb4[t] - m * sc;
  const float* wadvr = ws + O_WADVR;
  float s = 0.0f;
  for (int j = t; j < 9216; j += 256)
    s += (bf2f(y4b[n * 9216 + j]) * sc + sh) * wadvr[j];
  ss[t] = s; __syncthreads();
  for (int off = 128; off > 0; off >>= 1) {
    if (t < off) ss[t] += ss[t + off];
    __syncthreads();
  }
  if (t == 0) p.out[n] = ss[0] + p.badv[0];
}

extern "C" void kernel_launch(void* const* d_in, const int* in_sizes, int n_in,
                              void* d_out, int out_size, void* d_ws, size_t ws_size,
                              hipStream_t stream) {
  KParams prm;
  prm.x    = (const float*)d_in[0];
  prm.gd   = (const float*)d_in[1];
  prm.w1   = (const float*)d_in[2];
  prm.b1   = (const float*)d_in[3];
  prm.w2   = (const float*)d_in[4];
  prm.b2   = (const float*)d_in[5];
  prm.w3   = (const float*)d_in[6];
  prm.b3   = (const float*)d_in[7];
  prm.w4   = (const float*)d_in[8];
  prm.b4   = (const float*)d_in[9];
  prm.bg2  = (const float*)d_in[10];
  prm.bb2  = (const float*)d_in[11];
  prm.bg3  = (const float*)d_in[12];
  prm.bb3  = (const float*)d_in[13];
  prm.bg4  = (const float*)d_in[14];
  prm.bb4  = (const float*)d_in[15];
  prm.wadv = (const float*)d_in[16];
  prm.badv = (const float*)d_in[17];
  prm.out  = (float*)d_out;
  prm.ws   = (float*)d_ws;

  k_prep<<<10848, 256, 0, stream>>>(prm);
  k_s1<<<1262, 256, 0, stream>>>(prm);
  k_s2<<<980, 128, 0, stream>>>(prm);
  k_s3<<<288, 128, 0, stream>>>(prm);
  k_s4<<<128, 256, 0, stream>>>(prm);
}